// Round 1
// baseline (275.815 us; speedup 1.0000x reference)
//
#include <hip/hip_runtime.h>

typedef __bf16 bf16;
typedef __bf16 bf16x4 __attribute__((ext_vector_type(4)));
typedef __bf16 bf16x8 __attribute__((ext_vector_type(8)));
typedef float  f32x4  __attribute__((ext_vector_type(4)));

#define TOKENS 16384
#define D_IN   4096
#define D_OUT  4096
#define RANK   512

// Async global->LDS, 16B per lane. LDS dest must be wave-uniform base + lane*16
// (we pass per-lane ptrs that are exactly lane-linear, so HW semantics match).
__device__ inline void gload_lds16(const bf16* g, bf16* l) {
    __builtin_amdgcn_global_load_lds((const __attribute__((address_space(1))) void*)g,
                                     (__attribute__((address_space(3))) void*)l,
                                     16, 0, 0);
}

// ---------------------------------------------------------------------------
// Prep kernel 1: Vst[r][k] = bf16(V[k][r] * sigma[r])   (transpose + scale)
// V: [D_IN][RANK] f32 row-major -> Vst: [RANK][D_IN] bf16 (B^T layout for GEMM1)
// ---------------------------------------------------------------------------
__global__ __launch_bounds__(256) void vt_scale(const float* __restrict__ V,
                                                const float* __restrict__ sg,
                                                bf16* __restrict__ Vst) {
    __shared__ float tile[64][65];          // +1 pad: no bank conflicts
    const int tx = threadIdx.x & 63;
    const int ty = threadIdx.x >> 6;        // 0..3
    const int kb = blockIdx.x * 64;         // over D_IN
    const int rb = blockIdx.y * 64;         // over RANK
    const float s = sg[rb + tx];
#pragma unroll
    for (int i = ty; i < 64; i += 4)
        tile[i][tx] = V[(size_t)(kb + i) * RANK + rb + tx] * s;
    __syncthreads();
#pragma unroll
    for (int i = ty; i < 64; i += 4)
        Vst[(size_t)(rb + i) * D_IN + kb + tx] = (bf16)tile[tx][i];
}

// ---------------------------------------------------------------------------
// Prep kernel 2: elementwise f32 -> bf16 (U, already [D_OUT][RANK] = B^T form)
// ---------------------------------------------------------------------------
__global__ __launch_bounds__(256) void cvt_bf16_4(const float* __restrict__ in,
                                                  bf16* __restrict__ o, int n4) {
    int i = blockIdx.x * 256 + threadIdx.x;
    if (i < n4) {
        f32x4 v = *(const f32x4*)(in + (size_t)i * 4);
        bf16x4 b = { (bf16)v[0], (bf16)v[1], (bf16)v[2], (bf16)v[3] };
        *(bf16x4*)(o + (size_t)i * 4) = b;
    }
}

// ---------------------------------------------------------------------------
// m97-style GEMM: C[M][N] = A[M][K] @ B^T  (B given as [N][K], both bf16 in MFMA)
//   128x128 tile, BK=64, 256 threads = 4 waves (2x2), each wave 64x64 = 4x4
//   frags of mfma_f32_16x16x32_bf16. Single-buffered LDS (32 KiB).
//   A_F32: A is f32 in HBM, converted to bf16 during reg-staging.
//   OUT_BF16: store C as bf16 (else f32).
// ---------------------------------------------------------------------------
template <bool A_F32, bool OUT_BF16>
__global__ __launch_bounds__(256) void gemm_bt(const void* __restrict__ A_,
                                               const bf16* __restrict__ B,
                                               void* __restrict__ out_,
                                               int M, int N, int K) {
    __shared__ bf16 Al[128 * 64];
    __shared__ bf16 Bl[128 * 64];

    const int t  = threadIdx.x;
    const int l  = t & 63;
    const int w  = t >> 6;
    const int wr = w >> 1, wc = w & 1;
    const int lr = l & 15;   // row (A) / col (B) within fragment
    const int kg = l >> 4;   // k-group: lane holds k = kg*8 .. +8

    // XCD-aware bijective swizzle (gridDim.x % 8 == 0 for both our launches)
    const int nwg = gridDim.x;
    const int bid = blockIdx.x;
    const int cpx = nwg >> 3;
    const int swz = (bid & 7) * cpx + (bid >> 3);
    const int ntn = N >> 7;
    const int tm  = (swz / ntn) << 7;
    const int tn  = (swz % ntn) << 7;

    f32x4 acc[4][4] = {};

    for (int kt = 0; kt < K; kt += 64) {
        // ---- stage A tile [128][64] ----
        if constexpr (A_F32) {
            const float* Af = (const float*)A_;
#pragma unroll
            for (int c = 0; c < 8; ++c) {
                int j = c * 256 + t;
                int row = j >> 4, cg = j & 15;            // 16 chunks of 4 f32 per row
                f32x4 v = *(const f32x4*)(Af + (size_t)(tm + row) * K + kt + cg * 4);
                bf16x4 b = { (bf16)v[0], (bf16)v[1], (bf16)v[2], (bf16)v[3] };
                *(bf16x4*)&Al[row * 64 + cg * 4] = b;
            }
        } else {
            const bf16* Ab = (const bf16*)A_;
#pragma unroll
            for (int c = 0; c < 4; ++c) {
                int i = c * 256 + t;
                int row = i >> 3, g8 = i & 7;             // 8 chunks of 8 bf16 per row
                gload_lds16(Ab + (size_t)(tm + row) * K + kt + g8 * 8, &Al[i * 8]);
            }
        }
        // ---- stage B tile [128][64] ----
#pragma unroll
        for (int c = 0; c < 4; ++c) {
            int i = c * 256 + t;
            int row = i >> 3, g8 = i & 7;
            gload_lds16(B + (size_t)(tn + row) * K + kt + g8 * 8, &Bl[i * 8]);
        }
        __syncthreads();

        // ---- compute: 2 k-steps of 32 ----
#pragma unroll
        for (int ks = 0; ks < 2; ++ks) {
            bf16x8 af[4], bfr[4];
#pragma unroll
            for (int f = 0; f < 4; ++f) {
                af[f]  = *(const bf16x8*)&Al[(wr * 64 + f * 16 + lr) * 64 + ks * 32 + kg * 8];
                bfr[f] = *(const bf16x8*)&Bl[(wc * 64 + f * 16 + lr) * 64 + ks * 32 + kg * 8];
            }
#pragma unroll
            for (int fm = 0; fm < 4; ++fm)
#pragma unroll
                for (int fn = 0; fn < 4; ++fn)
                    acc[fm][fn] = __builtin_amdgcn_mfma_f32_16x16x32_bf16(
                        af[fm], bfr[fn], acc[fm][fn], 0, 0, 0);
        }
        __syncthreads();
    }

    // ---- epilogue: C/D layout col = lane&15, row = (lane>>4)*4 + reg ----
    const int r0 = tm + wr * 64 + kg * 4;
    const int c0 = tn + wc * 64 + lr;
#pragma unroll
    for (int fm = 0; fm < 4; ++fm)
#pragma unroll
        for (int fn = 0; fn < 4; ++fn)
#pragma unroll
            for (int r = 0; r < 4; ++r) {
                size_t idx = (size_t)(r0 + fm * 16 + r) * N + (c0 + fn * 16);
                if constexpr (OUT_BF16) ((bf16*)out_)[idx]  = (bf16)acc[fm][fn][r];
                else                    ((float*)out_)[idx] = acc[fm][fn][r];
            }
}

// ---------------------------------------------------------------------------
extern "C" void kernel_launch(void* const* d_in, const int* in_sizes, int n_in,
                              void* d_out, int out_size, void* d_ws, size_t ws_size,
                              hipStream_t stream) {
    const float* x  = (const float*)d_in[0];  // [16384][4096]
    const float* U  = (const float*)d_in[1];  // [4096][512]
    const float* sg = (const float*)d_in[2];  // [512]
    const float* V  = (const float*)d_in[3];  // [4096][512]
    float* out = (float*)d_out;               // [16384][4096] f32

    char* ws = (char*)d_ws;
    bf16* Vst = (bf16*)ws;                    // [512][4096]  = 4 MB
    bf16* Ub  = (bf16*)(ws + (4u << 20));     // [4096][512]  = 4 MB
    bf16* T   = (bf16*)(ws + (8u << 20));     // [16384][512] = 16 MB

    // Prep: Vst = (V * sigma)^T as bf16 ; Ub = bf16(U)
    vt_scale<<<dim3(D_IN / 64, RANK / 64), 256, 0, stream>>>(V, sg, Vst);
    cvt_bf16_4<<<(D_OUT * RANK / 4 + 255) / 256, 256, 0, stream>>>(U, Ub, D_OUT * RANK / 4);

    // GEMM1: T[16384][512] = bf16( x @ Vst^T )   (A f32->bf16 in staging)
    gemm_bt<true, true><<<(TOKENS / 128) * (RANK / 128), 256, 0, stream>>>(
        x, Vst, T, TOKENS, RANK, D_IN);

    // GEMM2: out[16384][4096] = T @ Ub^T  (f32 out)
    gemm_bt<false, false><<<(TOKENS / 128) * (D_OUT / 128), 256, 0, stream>>>(
        T, Ub, out, TOKENS, D_OUT, RANK);
}